// Round 10
// baseline (2212.688 us; speedup 1.0000x reference)
//
#include <hip/hip_runtime.h>
#include <cstdint>

#define N_PTS   8192
#define N_BATCH 8
#define NPOINT  2048
#define NSAMPLE 32
#define C_FEAT  64
#define R2      0.04f
#define FPS_T   1024
#define CH      (N_PTS / FPS_T)   // 8 points per thread = one chunk
#define NBINS   512               // 9-bit morton (3 bits/axis)
#define NWAVE   (FPS_T / 64)      // 16

static __device__ __forceinline__ uint32_t spread3(uint32_t v) {
  return (v & 1u) | ((v & 2u) << 2) | ((v & 4u) << 4);
}

static __device__ __forceinline__ uint32_t cell_of(float x, float y, float z) {
  int ix = (int)(x * 8.0f); ix = ix < 0 ? 0 : (ix > 7 ? 7 : ix);
  int iy = (int)(y * 8.0f); iy = iy < 0 ? 0 : (iy > 7 ? 7 : iy);
  int iz = (int)(z * 8.0f); iz = iz < 0 ? 0 : (iz > 7 ? 7 : iz);
  return spread3((uint32_t)ix) | (spread3((uint32_t)iy) << 1) | (spread3((uint32_t)iz) << 2);
}

// Wave-max step on packed positive f64 key via DPP (validated R2/R3/R6-R8).
#define DPP_MAXD(v, CTRL) do {                                                          \
  uint64_t u_ = __builtin_bit_cast(uint64_t, v);                                        \
  int lo_ = __builtin_amdgcn_update_dpp(0, (int)(uint32_t)u_,         CTRL, 0xF, 0xF, true); \
  int hi_ = __builtin_amdgcn_update_dpp(0, (int)(uint32_t)(u_ >> 32), CTRL, 0xF, 0xF, true); \
  double p_ = __builtin_bit_cast(double, ((uint64_t)(uint32_t)hi_ << 32) | (uint64_t)(uint32_t)lo_); \
  v = __builtin_fmax(v, p_);                                                            \
} while (0)

// ---------------------------------------------------------------------------
// FPS, one block per batch. R8's verified structure (f32 dist state, fmax
// tree + first-occurrence tie scan, DPP f64 key reduce, wave-level skip,
// parity slots, lane-parallel cross-wave reduce, exact bbox pruning) with
// ONE change: transposed chunk->wave ownership (chunk c = lane*NWAVE + w).
// Morton-adjacent (co-hot) chunks then belong to DIFFERENT waves, so the
// few active chunks per iteration update in parallel across waves instead
// of serially inside one straggler wave. Bit-exact: chunk contents and all
// per-chunk math unchanged; block max over all 1024 unique keys is
// partition-invariant -> identical far sequence.
// ---------------------------------------------------------------------------
__global__ __launch_bounds__(FPS_T) void fps_kernel(const float* __restrict__ xyz,
                                                    float* __restrict__ new_xyz) {
  __shared__ float sx[N_PTS], sy[N_PTS], sz[N_PTS];
  __shared__ int perm[N_PTS];          // setup only; reused as cent[] in loop
  __shared__ uint32_t bins[NBINS];
  __shared__ double pkey[2][NWAVE];
  float* cent = (float*)perm;          // [NPOINT*3] = 24 KB < 32 KB

  const int b = blockIdx.x;
  const int t = threadIdx.x;
  const int lane = t & 63;
  const int w = t >> 6;
  const float* xb = xyz + (size_t)b * N_PTS * 3;

  // ---- setup: stage coords ----
  for (int e = t; e < N_PTS * 3; e += FPS_T) {
    float v = xb[e];
    int p = e / 3, c = e - 3 * p;
    if (c == 0) sx[p] = v;
    else if (c == 1) sy[p] = v;
    else sz[p] = v;
  }
  if (t < NBINS) bins[t] = 0;
  __syncthreads();

  // ---- counting sort by morton cell: histogram ----
#pragma unroll
  for (int k = 0; k < CH; ++k) {
    int p = k * FPS_T + t;
    atomicAdd(&bins[cell_of(sx[p], sy[p], sz[p])], 1u);
  }
  __syncthreads();

  // ---- exclusive scan of 512 bins (wave 0, in place) ----
  if (t < 64) {
    uint32_t v[8], e[8], run = 0;
#pragma unroll
    for (int j = 0; j < 8; ++j) v[j] = bins[t * 8 + j];
#pragma unroll
    for (int j = 0; j < 8; ++j) { e[j] = run; run += v[j]; }
    uint32_t inc = run;
#pragma unroll
    for (int off = 1; off < 64; off <<= 1) {
      uint32_t o = __shfl_up(inc, off, 64);
      if (t >= off) inc += o;
    }
    uint32_t base = inc - run;
#pragma unroll
    for (int j = 0; j < 8; ++j) bins[t * 8 + j] = base + e[j];
  }
  __syncthreads();

  // ---- scatter permutation ----
#pragma unroll
  for (int k = 0; k < CH; ++k) {
    int p = k * FPS_T + t;
    uint32_t pos = atomicAdd(&bins[cell_of(sx[p], sy[p], sz[p])], 1u);
    perm[pos] = p;
  }
  __syncthreads();

  // ---- load chunk into registers, compute bbox ----
  // TRANSPOSED ownership: chunk index c = lane*NWAVE + w. Consecutive
  // (Morton-adjacent) chunks map to different waves.
  const int c = lane * NWAVE + w;
  float rx[CH], ry[CH], rz[CH], dist[CH];
  uint32_t ridx[CH];
#pragma unroll
  for (int j = 0; j < CH; ++j) {
    int p = perm[CH * c + j];
    ridx[j] = (uint32_t)p;
    rx[j] = sx[p]; ry[j] = sy[p]; rz[j] = sz[p];
    dist[j] = __builtin_inff();
  }
  float bnx = rx[0], bxx = rx[0], bny = ry[0], bxy = ry[0], bnz = rz[0], bxz = rz[0];
#pragma unroll
  for (int j = 1; j < CH; ++j) {
    bnx = fminf(bnx, rx[j]); bxx = fmaxf(bxx, rx[j]);
    bny = fminf(bny, ry[j]); bxy = fmaxf(bxy, ry[j]);
    bnz = fminf(bnz, rz[j]); bxz = fmaxf(bxz, rz[j]);
  }
  __syncthreads();   // perm fully consumed; cent alias is now safe

  float cmax = __builtin_inff();   // chunk max dist (cached)
  uint32_t cidx = 0;               // chunk argmax orig idx (cached)
  double wkey = 0.0;               // cached wave-reduced key (lane 63 valid)
  int far = 0;

  for (int it = 0; it < NPOINT; ++it) {
    float cx = sx[far], cy = sy[far], cz = sz[far];
    if (t == 0) {   // LDS staging only -- no global store in the loop
      cent[it * 3 + 0] = cx;
      cent[it * 3 + 1] = cy;
      cent[it * 3 + 2] = cz;
    }

    // conservative lower bound of any d2 in this chunk (margin 1e-5 >> fp err)
    float gx = fmaxf(fmaxf(bnx - cx, cx - bxx), 0.0f);
    float gy = fmaxf(fmaxf(bny - cy, cy - bxy), 0.0f);
    float gz = fmaxf(fmaxf(bnz - cz, cz - bxz), 0.0f);
    float lb = gx * gx + gy * gy + gz * gz;

    bool act = !(lb * 0.99999f >= cmax);
    uint64_t am = __ballot(act);
    if (am != 0) {     // wave-uniform: some lane's cached key changes
      if (act) {
        {
#pragma clang fp contract(off)
#pragma unroll
          for (int j = 0; j < CH; ++j) {
            float dx = rx[j] - cx;
            float a = dx * dx;
            float dy = ry[j] - cy;
            a = a + dy * dy;         // exact left-to-right, no FMA
            float dz = rz[j] - cz;
            a = a + dz * dz;
            dist[j] = fminf(dist[j], a);
          }
        }
        // chunk max (tree) + first-occurrence (min orig idx) tie resolution
        float m0 = fmaxf(dist[0], dist[1]), m1 = fmaxf(dist[2], dist[3]);
        float m2 = fmaxf(dist[4], dist[5]), m3 = fmaxf(dist[6], dist[7]);
        cmax = fmaxf(fmaxf(m0, m1), fmaxf(m2, m3));
        uint32_t mi = 0xFFFFFFFFu;
#pragma unroll
        for (int j = 0; j < CH; ++j) {
          uint32_t cand = ridx[j] < mi ? ridx[j] : mi;
          mi = (dist[j] == cmax) ? cand : mi;
        }
        cidx = mi;
      }
      // wave reduce over ALL lanes' cached keys (active lanes just updated)
      double key = __builtin_bit_cast(double,
          ((uint64_t)__builtin_bit_cast(uint32_t, cmax) << 32) |
          (uint64_t)(0xFFFFFFFFu - cidx));
      DPP_MAXD(key, 0x111);   // row_shr 1
      DPP_MAXD(key, 0x112);   // row_shr 2
      DPP_MAXD(key, 0x114);   // row_shr 4
      DPP_MAXD(key, 0x118);   // row_shr 8
      DPP_MAXD(key, 0x142);   // row_bcast 15
      DPP_MAXD(key, 0x143);   // row_bcast 31  -> lane 63 has wave max
      wkey = key;             // cache (lane 63's copy is the wave max)
    }
    if (lane == 63) pkey[it & 1][w] = wkey;
    __syncthreads();

    // lane-parallel cross-wave reduce: lane reads slot (lane&15); 4-step DPP
    // row-reduce puts the max of all 16 slots in lane 15 of every row.
    double g = pkey[it & 1][lane & 15];
    DPP_MAXD(g, 0x111);
    DPP_MAXD(g, 0x112);
    DPP_MAXD(g, 0x114);
    DPP_MAXD(g, 0x118);
    uint64_t gu = __builtin_bit_cast(uint64_t, g);
    uint32_t glo = (uint32_t)__builtin_amdgcn_readlane((int)(uint32_t)gu, 15);
    far = (int)(0xFFFFFFFFu - glo);
  }

  // ---- one-time coalesced copy-out of staged centroids ----
  __syncthreads();
  float* ob = new_xyz + (size_t)b * NPOINT * 3;
  for (int e = t; e < NPOINT * 3; e += FPS_T) ob[e] = cent[e];
}

// ---------------------------------------------------------------------------
// Ball query + gather + concat, one wave per query (unchanged, verified).
// ---------------------------------------------------------------------------
__global__ __launch_bounds__(256) void ball_group_kernel(const float* __restrict__ xyz,
                                                         const float* __restrict__ points,
                                                         const float* __restrict__ new_xyz,
                                                         float* __restrict__ out_np) {
  __shared__ int list[4][NSAMPLE];
  const int wslot = threadIdx.x >> 6;
  const int lane = threadIdx.x & 63;
  const int qg = blockIdx.x * 4 + wslot;
  const int b = qg >> 11;

  const float* xb = xyz + (size_t)b * N_PTS * 3;
  const float* nq = new_xyz + (size_t)qg * 3;
  const float cqx = nq[0], cqy = nq[1], cqz = nq[2];

  int K = 0;
  {
#pragma clang fp contract(off)
    for (int c = 0; c < N_PTS / 64; ++c) {
      const int pt = c * 64 + lane;
      const float* p = xb + pt * 3;
      float dx = cqx - p[0];
      float dy = cqy - p[1];
      float dz = cqz - p[2];
      float d2 = dx * dx;
      d2 = d2 + dy * dy;
      d2 = d2 + dz * dz;
      bool in = d2 < R2;
      unsigned long long mask = __ballot(in);
      if (in) {
        int rank = __builtin_amdgcn_mbcnt_hi((uint32_t)(mask >> 32),
                     __builtin_amdgcn_mbcnt_lo((uint32_t)mask, 0));
        int s = K + rank;
        if (s < NSAMPLE) list[wslot][s] = pt;
      }
      K += (int)__popcll(mask);
      if (K >= NSAMPLE) break;   // wave-uniform
    }
  }
  __builtin_amdgcn_wave_barrier();
  int Kc = K < NSAMPLE ? K : NSAMPLE;
  int first = list[wslot][0];
  if (lane >= Kc && lane < NSAMPLE) list[wslot][lane] = first;
  __builtin_amdgcn_wave_barrier();

  const float* pb = points + (size_t)b * N_PTS * C_FEAT;
  float* oq = out_np + (size_t)qg * (NSAMPLE * 67);
  for (int r = 0; r < 34; ++r) {
    int tt = r * 64 + lane;
    if (tt < NSAMPLE * 67) {
      int s = tt / 67;
      int f = tt - s * 67;
      int idx = list[wslot][s];
      float val;
      if (f < 3) {
        float cf = (f == 0) ? cqx : ((f == 1) ? cqy : cqz);
        val = xb[idx * 3 + f] - cf;
      } else {
        val = pb[(size_t)idx * C_FEAT + (f - 3)];
      }
      oq[tt] = val;
    }
  }
}

extern "C" void kernel_launch(void* const* d_in, const int* in_sizes, int n_in,
                              void* d_out, int out_size, void* d_ws, size_t ws_size,
                              hipStream_t stream) {
  const float* xyz = (const float*)d_in[0];
  const float* points = (const float*)d_in[1];
  float* out = (float*)d_out;
  float* new_xyz = out;
  float* new_points = out + (size_t)N_BATCH * NPOINT * 3;

  fps_kernel<<<N_BATCH, FPS_T, 0, stream>>>(xyz, new_xyz);
  ball_group_kernel<<<(N_BATCH * NPOINT) / 4, 256, 0, stream>>>(xyz, points, new_xyz, new_points);
}

// Round 11
// 2001.758 us; speedup vs baseline: 1.1054x; 1.1054x over previous
//
#include <hip/hip_runtime.h>
#include <cstdint>

#define N_PTS   8192
#define N_BATCH 8
#define NPOINT  2048
#define NSAMPLE 32
#define C_FEAT  64
#define R2      0.04f
#define FPS_T   512
#define CH      (N_PTS / FPS_T)   // 16 points per thread = one chunk
#define NBINS   512               // 9-bit morton (3 bits/axis)
#define NWAVE   (FPS_T / 64)      // 8

static __device__ __forceinline__ uint32_t spread3(uint32_t v) {
  return (v & 1u) | ((v & 2u) << 2) | ((v & 4u) << 4);
}

static __device__ __forceinline__ uint32_t cell_of(float x, float y, float z) {
  int ix = (int)(x * 8.0f); ix = ix < 0 ? 0 : (ix > 7 ? 7 : ix);
  int iy = (int)(y * 8.0f); iy = iy < 0 ? 0 : (iy > 7 ? 7 : iy);
  int iz = (int)(z * 8.0f); iz = iz < 0 ? 0 : (iz > 7 ? 7 : iz);
  return spread3((uint32_t)ix) | (spread3((uint32_t)iy) << 1) | (spread3((uint32_t)iz) << 2);
}

// Wave-max step on packed positive f64 key via DPP (validated R2/R3/R6-R10).
#define DPP_MAXD(v, CTRL) do {                                                          \
  uint64_t u_ = __builtin_bit_cast(uint64_t, v);                                        \
  int lo_ = __builtin_amdgcn_update_dpp(0, (int)(uint32_t)u_,         CTRL, 0xF, 0xF, true); \
  int hi_ = __builtin_amdgcn_update_dpp(0, (int)(uint32_t)(u_ >> 32), CTRL, 0xF, 0xF, true); \
  double p_ = __builtin_bit_cast(double, ((uint64_t)(uint32_t)hi_ << 32) | (uint64_t)(uint32_t)lo_); \
  v = __builtin_fmax(v, p_);                                                            \
} while (0)

// ---------------------------------------------------------------------------
// FPS, one block per batch. R8's verified structure (f32 dist state, fmax
// tree + first-occurrence tie scan, DPP f64 key reduce, wave-level skip with
// chunk c = t concentration, parity slots, lane-parallel cross-wave reduce,
// exact bbox pruning) re-parameterized to 512 threads / 8 waves / CH=16:
// halves the replicated fixed-path issue (2 waves/SIMD instead of 4) while
// concentration keeps ~1 wave on the expensive update path. Coords stored
// interleaved (input layout); lb via fmed3 (gate-only, margin-covered).
// Per-point d2 math / key packing / reduce semantics bit-identical to R8.
// ---------------------------------------------------------------------------
__global__ __launch_bounds__(FPS_T) void fps_kernel(const float* __restrict__ xyz,
                                                    float* __restrict__ new_xyz) {
  __shared__ float scrd[N_PTS * 3];    // interleaved x,y,z (input layout)
  __shared__ int perm[N_PTS];          // setup only; reused as cent[] in loop
  __shared__ uint32_t bins[NBINS];
  __shared__ double pkey[2][NWAVE];
  float* cent = (float*)perm;          // [NPOINT*3] = 24 KB < 32 KB

  const int b = blockIdx.x;
  const int t = threadIdx.x;
  const int lane = t & 63;
  const int w = t >> 6;
  const float* xb = xyz + (size_t)b * N_PTS * 3;

  // ---- setup: stage coords (direct copy, input is already interleaved) ----
  for (int e = t; e < N_PTS * 3; e += FPS_T) scrd[e] = xb[e];
  bins[t] = 0;            // FPS_T == NBINS
  __syncthreads();

  // ---- counting sort by morton cell: histogram ----
#pragma unroll
  for (int k = 0; k < CH; ++k) {
    int p = k * FPS_T + t;
    atomicAdd(&bins[cell_of(scrd[3 * p], scrd[3 * p + 1], scrd[3 * p + 2])], 1u);
  }
  __syncthreads();

  // ---- exclusive scan of 512 bins (wave 0, in place) ----
  if (t < 64) {
    uint32_t v[8], e[8], run = 0;
#pragma unroll
    for (int j = 0; j < 8; ++j) v[j] = bins[t * 8 + j];
#pragma unroll
    for (int j = 0; j < 8; ++j) { e[j] = run; run += v[j]; }
    uint32_t inc = run;
#pragma unroll
    for (int off = 1; off < 64; off <<= 1) {
      uint32_t o = __shfl_up(inc, off, 64);
      if (t >= off) inc += o;
    }
    uint32_t base = inc - run;
#pragma unroll
    for (int j = 0; j < 8; ++j) bins[t * 8 + j] = base + e[j];
  }
  __syncthreads();

  // ---- scatter permutation ----
#pragma unroll
  for (int k = 0; k < CH; ++k) {
    int p = k * FPS_T + t;
    uint32_t pos = atomicAdd(&bins[cell_of(scrd[3 * p], scrd[3 * p + 1], scrd[3 * p + 2])], 1u);
    perm[pos] = p;
  }
  __syncthreads();

  // ---- load chunk into registers (c = t: Morton-concentrated), bbox ----
  float rx[CH], ry[CH], rz[CH], dist[CH];
  uint32_t ridx[CH];
#pragma unroll
  for (int j = 0; j < CH; ++j) {
    int p = perm[CH * t + j];
    ridx[j] = (uint32_t)p;
    rx[j] = scrd[3 * p]; ry[j] = scrd[3 * p + 1]; rz[j] = scrd[3 * p + 2];
    dist[j] = __builtin_inff();
  }
  float bnx = rx[0], bxx = rx[0], bny = ry[0], bxy = ry[0], bnz = rz[0], bxz = rz[0];
#pragma unroll
  for (int j = 1; j < CH; ++j) {
    bnx = fminf(bnx, rx[j]); bxx = fmaxf(bxx, rx[j]);
    bny = fminf(bny, ry[j]); bxy = fmaxf(bxy, ry[j]);
    bnz = fminf(bnz, rz[j]); bxz = fmaxf(bxz, rz[j]);
  }
  __syncthreads();   // perm fully consumed; cent alias is now safe

  float cmax = __builtin_inff();   // chunk max dist (cached)
  uint32_t cidx = 0;               // chunk argmax orig idx (cached)
  double wkey = 0.0;               // cached wave-reduced key (lane 63 valid)
  int far = 0;

  for (int it = 0; it < NPOINT; ++it) {
    float cx = scrd[3 * far], cy = scrd[3 * far + 1], cz = scrd[3 * far + 2];
    if (t == 0) {   // LDS staging only -- no global store in the loop
      cent[it * 3 + 0] = cx;
      cent[it * 3 + 1] = cy;
      cent[it * 3 + 2] = cz;
    }

    // conservative lower bound of any d2 in this chunk: gate-only (1e-5
    // margin >> fp error), sign-free via med3 (gx^2 == (dist-to-slab)^2)
    float gx = cx - __builtin_amdgcn_fmed3f(cx, bnx, bxx);
    float gy = cy - __builtin_amdgcn_fmed3f(cy, bny, bxy);
    float gz = cz - __builtin_amdgcn_fmed3f(cz, bnz, bxz);
    float lb = gx * gx + gy * gy + gz * gz;

    bool act = !(lb * 0.99999f >= cmax);
    uint64_t am = __ballot(act);
    if (am != 0) {     // wave-uniform: some lane's cached key changes
      if (act) {
        {
#pragma clang fp contract(off)
#pragma unroll
          for (int j = 0; j < CH; ++j) {
            float dx = rx[j] - cx;
            float a = dx * dx;
            float dy = ry[j] - cy;
            a = a + dy * dy;         // exact left-to-right, no FMA
            float dz = rz[j] - cz;
            a = a + dz * dz;
            dist[j] = fminf(dist[j], a);
          }
        }
        // chunk max (tree) + first-occurrence (min orig idx) tie resolution
        float m0 = fmaxf(dist[0], dist[1]),  m1 = fmaxf(dist[2], dist[3]);
        float m2 = fmaxf(dist[4], dist[5]),  m3 = fmaxf(dist[6], dist[7]);
        float m4 = fmaxf(dist[8], dist[9]),  m5 = fmaxf(dist[10], dist[11]);
        float m6 = fmaxf(dist[12], dist[13]), m7 = fmaxf(dist[14], dist[15]);
        m0 = fmaxf(m0, m1); m2 = fmaxf(m2, m3); m4 = fmaxf(m4, m5); m6 = fmaxf(m6, m7);
        cmax = fmaxf(fmaxf(m0, m2), fmaxf(m4, m6));
        uint32_t mi = 0xFFFFFFFFu;
#pragma unroll
        for (int j = 0; j < CH; ++j) {
          uint32_t cand = ridx[j] < mi ? ridx[j] : mi;
          mi = (dist[j] == cmax) ? cand : mi;
        }
        cidx = mi;
      }
      // wave reduce over ALL lanes' cached keys (active lanes just updated)
      double key = __builtin_bit_cast(double,
          ((uint64_t)__builtin_bit_cast(uint32_t, cmax) << 32) |
          (uint64_t)(0xFFFFFFFFu - cidx));
      DPP_MAXD(key, 0x111);   // row_shr 1
      DPP_MAXD(key, 0x112);   // row_shr 2
      DPP_MAXD(key, 0x114);   // row_shr 4
      DPP_MAXD(key, 0x118);   // row_shr 8
      DPP_MAXD(key, 0x142);   // row_bcast 15
      DPP_MAXD(key, 0x143);   // row_bcast 31  -> lane 63 has wave max
      wkey = key;             // cache (lane 63's copy is the wave max)
    }
    if (lane == 63) pkey[it & 1][w] = wkey;
    __syncthreads();

    // lane-parallel cross-wave reduce: lane reads slot (lane&7); 3-step DPP
    // row-reduce puts the max of all 8 slots in lane 7 of every 16-lane row.
    double g = pkey[it & 1][lane & 7];
    DPP_MAXD(g, 0x111);
    DPP_MAXD(g, 0x112);
    DPP_MAXD(g, 0x114);
    uint64_t gu = __builtin_bit_cast(uint64_t, g);
    uint32_t glo = (uint32_t)__builtin_amdgcn_readlane((int)(uint32_t)gu, 7);
    far = (int)(0xFFFFFFFFu - glo);
  }

  // ---- one-time coalesced copy-out of staged centroids ----
  __syncthreads();
  float* ob = new_xyz + (size_t)b * NPOINT * 3;
  for (int e = t; e < NPOINT * 3; e += FPS_T) ob[e] = cent[e];
}

// ---------------------------------------------------------------------------
// Ball query + gather + concat, one wave per query (unchanged, verified).
// ---------------------------------------------------------------------------
__global__ __launch_bounds__(256) void ball_group_kernel(const float* __restrict__ xyz,
                                                         const float* __restrict__ points,
                                                         const float* __restrict__ new_xyz,
                                                         float* __restrict__ out_np) {
  __shared__ int list[4][NSAMPLE];
  const int wslot = threadIdx.x >> 6;
  const int lane = threadIdx.x & 63;
  const int qg = blockIdx.x * 4 + wslot;
  const int b = qg >> 11;

  const float* xb = xyz + (size_t)b * N_PTS * 3;
  const float* nq = new_xyz + (size_t)qg * 3;
  const float cqx = nq[0], cqy = nq[1], cqz = nq[2];

  int K = 0;
  {
#pragma clang fp contract(off)
    for (int c = 0; c < N_PTS / 64; ++c) {
      const int pt = c * 64 + lane;
      const float* p = xb + pt * 3;
      float dx = cqx - p[0];
      float dy = cqy - p[1];
      float dz = cqz - p[2];
      float d2 = dx * dx;
      d2 = d2 + dy * dy;
      d2 = d2 + dz * dz;
      bool in = d2 < R2;
      unsigned long long mask = __ballot(in);
      if (in) {
        int rank = __builtin_amdgcn_mbcnt_hi((uint32_t)(mask >> 32),
                     __builtin_amdgcn_mbcnt_lo((uint32_t)mask, 0));
        int s = K + rank;
        if (s < NSAMPLE) list[wslot][s] = pt;
      }
      K += (int)__popcll(mask);
      if (K >= NSAMPLE) break;   // wave-uniform
    }
  }
  __builtin_amdgcn_wave_barrier();
  int Kc = K < NSAMPLE ? K : NSAMPLE;
  int first = list[wslot][0];
  if (lane >= Kc && lane < NSAMPLE) list[wslot][lane] = first;
  __builtin_amdgcn_wave_barrier();

  const float* pb = points + (size_t)b * N_PTS * C_FEAT;
  float* oq = out_np + (size_t)qg * (NSAMPLE * 67);
  for (int r = 0; r < 34; ++r) {
    int tt = r * 64 + lane;
    if (tt < NSAMPLE * 67) {
      int s = tt / 67;
      int f = tt - s * 67;
      int idx = list[wslot][s];
      float val;
      if (f < 3) {
        float cf = (f == 0) ? cqx : ((f == 1) ? cqy : cqz);
        val = xb[idx * 3 + f] - cf;
      } else {
        val = pb[(size_t)idx * C_FEAT + (f - 3)];
      }
      oq[tt] = val;
    }
  }
}

extern "C" void kernel_launch(void* const* d_in, const int* in_sizes, int n_in,
                              void* d_out, int out_size, void* d_ws, size_t ws_size,
                              hipStream_t stream) {
  const float* xyz = (const float*)d_in[0];
  const float* points = (const float*)d_in[1];
  float* out = (float*)d_out;
  float* new_xyz = out;
  float* new_points = out + (size_t)N_BATCH * NPOINT * 3;

  fps_kernel<<<N_BATCH, FPS_T, 0, stream>>>(xyz, new_xyz);
  ball_group_kernel<<<(N_BATCH * NPOINT) / 4, 256, 0, stream>>>(xyz, points, new_xyz, new_points);
}

// Round 12
// 1456.306 us; speedup vs baseline: 1.5194x; 1.3745x over previous
//
#include <hip/hip_runtime.h>
#include <cstdint>

#define N_PTS   8192
#define N_BATCH 8
#define NPOINT  2048
#define NSAMPLE 32
#define C_FEAT  64
#define R2      0.04f
#define FPS_T   1024
#define CH      (N_PTS / FPS_T)   // 8 points per thread = one chunk
#define NBINS   4096              // 12-bit morton (4 bits/axis)
#define NWAVE   (FPS_T / 64)      // 16

static __device__ __forceinline__ uint32_t spread4(uint32_t v) {
  // 4 bits -> positions 0,3,6,9
  return (v & 1u) | ((v & 2u) << 2) | ((v & 4u) << 4) | ((v & 8u) << 6);
}

static __device__ __forceinline__ uint32_t cell_of(float x, float y, float z) {
  int ix = (int)(x * 16.0f); ix = ix < 0 ? 0 : (ix > 15 ? 15 : ix);
  int iy = (int)(y * 16.0f); iy = iy < 0 ? 0 : (iy > 15 ? 15 : iy);
  int iz = (int)(z * 16.0f); iz = iz < 0 ? 0 : (iz > 15 ? 15 : iz);
  return spread4((uint32_t)ix) | (spread4((uint32_t)iy) << 1) | (spread4((uint32_t)iz) << 2);
}

// Wave-max step on packed positive f64 key via DPP (validated R2/R3/R6-R11).
#define DPP_MAXD(v, CTRL) do {                                                          \
  uint64_t u_ = __builtin_bit_cast(uint64_t, v);                                        \
  int lo_ = __builtin_amdgcn_update_dpp(0, (int)(uint32_t)u_,         CTRL, 0xF, 0xF, true); \
  int hi_ = __builtin_amdgcn_update_dpp(0, (int)(uint32_t)(u_ >> 32), CTRL, 0xF, 0xF, true); \
  double p_ = __builtin_bit_cast(double, ((uint64_t)(uint32_t)hi_ << 32) | (uint64_t)(uint32_t)lo_); \
  v = __builtin_fmax(v, p_);                                                            \
} while (0)

// ---------------------------------------------------------------------------
// FPS, one block per batch. R8's verified structure VERBATIM (f32 dist state,
// fmax tree + first-occurrence tie scan, DPP f64 key reduce, wave-level skip
// with chunk c = t concentration, parity slots, lane-parallel cross-wave
// reduce, sx[far] centroid reads). Two structure-preserving trims:
//  (1) 4096-cell morton sort (tighter chunk bboxes -> higher wave-skip rate;
//      partition-invariant -> identical far sequence),
//  (2) fmed3 slab distance for lb (same value squared, 6 fewer fixed-path
//      insts; gate-only with 1e-5 margin, verified absmax-0 in R11).
// ---------------------------------------------------------------------------
__global__ __launch_bounds__(FPS_T) void fps_kernel(const float* __restrict__ xyz,
                                                    float* __restrict__ new_xyz) {
  __shared__ float sx[N_PTS], sy[N_PTS], sz[N_PTS];
  __shared__ int perm[N_PTS];          // setup only; reused as cent[] in loop
  __shared__ uint32_t bins[NBINS];
  __shared__ double pkey[2][NWAVE];
  float* cent = (float*)perm;          // [NPOINT*3] = 24 KB < 32 KB

  const int b = blockIdx.x;
  const int t = threadIdx.x;
  const int lane = t & 63;
  const int w = t >> 6;
  const float* xb = xyz + (size_t)b * N_PTS * 3;

  // ---- setup: stage coords ----
  for (int e = t; e < N_PTS * 3; e += FPS_T) {
    float v = xb[e];
    int p = e / 3, c = e - 3 * p;
    if (c == 0) sx[p] = v;
    else if (c == 1) sy[p] = v;
    else sz[p] = v;
  }
#pragma unroll
  for (int k = 0; k < NBINS / FPS_T; ++k) bins[k * FPS_T + t] = 0;
  __syncthreads();

  // ---- counting sort by morton cell: histogram ----
#pragma unroll
  for (int k = 0; k < CH; ++k) {
    int p = k * FPS_T + t;
    atomicAdd(&bins[cell_of(sx[p], sy[p], sz[p])], 1u);
  }
  __syncthreads();

  // ---- exclusive scan of 4096 bins (wave 0; 64 bins/lane, two-pass) ----
  if (t < 64) {
    uint32_t sum = 0;
    for (int j = 0; j < 64; ++j) sum += bins[t * 64 + j];
    uint32_t inc = sum;
#pragma unroll
    for (int off = 1; off < 64; off <<= 1) {
      uint32_t o = __shfl_up(inc, off, 64);
      if (t >= off) inc += o;
    }
    uint32_t run = inc - sum;   // exclusive base for this lane's 64 bins
    for (int j = 0; j < 64; ++j) {
      uint32_t v = bins[t * 64 + j];
      bins[t * 64 + j] = run;
      run += v;
    }
  }
  __syncthreads();

  // ---- scatter permutation ----
#pragma unroll
  for (int k = 0; k < CH; ++k) {
    int p = k * FPS_T + t;
    uint32_t pos = atomicAdd(&bins[cell_of(sx[p], sy[p], sz[p])], 1u);
    perm[pos] = p;
  }
  __syncthreads();

  // ---- load chunk into registers (c = t: Morton-concentrated), bbox ----
  float rx[CH], ry[CH], rz[CH], dist[CH];
  uint32_t ridx[CH];
#pragma unroll
  for (int j = 0; j < CH; ++j) {
    int p = perm[CH * t + j];
    ridx[j] = (uint32_t)p;
    rx[j] = sx[p]; ry[j] = sy[p]; rz[j] = sz[p];
    dist[j] = __builtin_inff();
  }
  float bnx = rx[0], bxx = rx[0], bny = ry[0], bxy = ry[0], bnz = rz[0], bxz = rz[0];
#pragma unroll
  for (int j = 1; j < CH; ++j) {
    bnx = fminf(bnx, rx[j]); bxx = fmaxf(bxx, rx[j]);
    bny = fminf(bny, ry[j]); bxy = fmaxf(bxy, ry[j]);
    bnz = fminf(bnz, rz[j]); bxz = fmaxf(bxz, rz[j]);
  }
  __syncthreads();   // perm fully consumed; cent alias is now safe

  float cmax = __builtin_inff();   // chunk max dist (cached)
  uint32_t cidx = 0;               // chunk argmax orig idx (cached)
  double wkey = 0.0;               // cached wave-reduced key (lane 63 valid)
  int far = 0;

  for (int it = 0; it < NPOINT; ++it) {
    float cx = sx[far], cy = sy[far], cz = sz[far];
    if (t == 0) {   // LDS staging only -- no global store in the loop
      cent[it * 3 + 0] = cx;
      cent[it * 3 + 1] = cy;
      cent[it * 3 + 2] = cz;
    }

    // conservative lower bound of any d2 in this chunk: slab distance via
    // med3 (sign-free, squares away); gate-only, 1e-5 margin >> fp error
    float gx = cx - __builtin_amdgcn_fmed3f(cx, bnx, bxx);
    float gy = cy - __builtin_amdgcn_fmed3f(cy, bny, bxy);
    float gz = cz - __builtin_amdgcn_fmed3f(cz, bnz, bxz);
    float lb = gx * gx + gy * gy + gz * gz;

    bool act = !(lb * 0.99999f >= cmax);
    uint64_t am = __ballot(act);
    if (am != 0) {     // wave-uniform: some lane's cached key changes
      if (act) {
        {
#pragma clang fp contract(off)
#pragma unroll
          for (int j = 0; j < CH; ++j) {
            float dx = rx[j] - cx;
            float a = dx * dx;
            float dy = ry[j] - cy;
            a = a + dy * dy;         // exact left-to-right, no FMA
            float dz = rz[j] - cz;
            a = a + dz * dz;
            dist[j] = fminf(dist[j], a);
          }
        }
        // chunk max (tree) + first-occurrence (min orig idx) tie resolution
        float m0 = fmaxf(dist[0], dist[1]), m1 = fmaxf(dist[2], dist[3]);
        float m2 = fmaxf(dist[4], dist[5]), m3 = fmaxf(dist[6], dist[7]);
        cmax = fmaxf(fmaxf(m0, m1), fmaxf(m2, m3));
        uint32_t mi = 0xFFFFFFFFu;
#pragma unroll
        for (int j = 0; j < CH; ++j) {
          uint32_t cand = ridx[j] < mi ? ridx[j] : mi;
          mi = (dist[j] == cmax) ? cand : mi;
        }
        cidx = mi;
      }
      // wave reduce over ALL lanes' cached keys (active lanes just updated)
      double key = __builtin_bit_cast(double,
          ((uint64_t)__builtin_bit_cast(uint32_t, cmax) << 32) |
          (uint64_t)(0xFFFFFFFFu - cidx));
      DPP_MAXD(key, 0x111);   // row_shr 1
      DPP_MAXD(key, 0x112);   // row_shr 2
      DPP_MAXD(key, 0x114);   // row_shr 4
      DPP_MAXD(key, 0x118);   // row_shr 8
      DPP_MAXD(key, 0x142);   // row_bcast 15
      DPP_MAXD(key, 0x143);   // row_bcast 31  -> lane 63 has wave max
      wkey = key;             // cache (lane 63's copy is the wave max)
    }
    if (lane == 63) pkey[it & 1][w] = wkey;
    __syncthreads();

    // lane-parallel cross-wave reduce: lane reads slot (lane&15); 4-step DPP
    // row-reduce puts the max of all 16 slots in lane 15 of every row.
    double g = pkey[it & 1][lane & 15];
    DPP_MAXD(g, 0x111);
    DPP_MAXD(g, 0x112);
    DPP_MAXD(g, 0x114);
    DPP_MAXD(g, 0x118);
    uint64_t gu = __builtin_bit_cast(uint64_t, g);
    uint32_t glo = (uint32_t)__builtin_amdgcn_readlane((int)(uint32_t)gu, 15);
    far = (int)(0xFFFFFFFFu - glo);
  }

  // ---- one-time coalesced copy-out of staged centroids ----
  __syncthreads();
  float* ob = new_xyz + (size_t)b * NPOINT * 3;
  for (int e = t; e < NPOINT * 3; e += FPS_T) ob[e] = cent[e];
}

// ---------------------------------------------------------------------------
// Ball query + gather + concat, one wave per query (unchanged, verified).
// ---------------------------------------------------------------------------
__global__ __launch_bounds__(256) void ball_group_kernel(const float* __restrict__ xyz,
                                                         const float* __restrict__ points,
                                                         const float* __restrict__ new_xyz,
                                                         float* __restrict__ out_np) {
  __shared__ int list[4][NSAMPLE];
  const int wslot = threadIdx.x >> 6;
  const int lane = threadIdx.x & 63;
  const int qg = blockIdx.x * 4 + wslot;
  const int b = qg >> 11;

  const float* xb = xyz + (size_t)b * N_PTS * 3;
  const float* nq = new_xyz + (size_t)qg * 3;
  const float cqx = nq[0], cqy = nq[1], cqz = nq[2];

  int K = 0;
  {
#pragma clang fp contract(off)
    for (int c = 0; c < N_PTS / 64; ++c) {
      const int pt = c * 64 + lane;
      const float* p = xb + pt * 3;
      float dx = cqx - p[0];
      float dy = cqy - p[1];
      float dz = cqz - p[2];
      float d2 = dx * dx;
      d2 = d2 + dy * dy;
      d2 = d2 + dz * dz;
      bool in = d2 < R2;
      unsigned long long mask = __ballot(in);
      if (in) {
        int rank = __builtin_amdgcn_mbcnt_hi((uint32_t)(mask >> 32),
                     __builtin_amdgcn_mbcnt_lo((uint32_t)mask, 0));
        int s = K + rank;
        if (s < NSAMPLE) list[wslot][s] = pt;
      }
      K += (int)__popcll(mask);
      if (K >= NSAMPLE) break;   // wave-uniform
    }
  }
  __builtin_amdgcn_wave_barrier();
  int Kc = K < NSAMPLE ? K : NSAMPLE;
  int first = list[wslot][0];
  if (lane >= Kc && lane < NSAMPLE) list[wslot][lane] = first;
  __builtin_amdgcn_wave_barrier();

  const float* pb = points + (size_t)b * N_PTS * C_FEAT;
  float* oq = out_np + (size_t)qg * (NSAMPLE * 67);
  for (int r = 0; r < 34; ++r) {
    int tt = r * 64 + lane;
    if (tt < NSAMPLE * 67) {
      int s = tt / 67;
      int f = tt - s * 67;
      int idx = list[wslot][s];
      float val;
      if (f < 3) {
        float cf = (f == 0) ? cqx : ((f == 1) ? cqy : cqz);
        val = xb[idx * 3 + f] - cf;
      } else {
        val = pb[(size_t)idx * C_FEAT + (f - 3)];
      }
      oq[tt] = val;
    }
  }
}

extern "C" void kernel_launch(void* const* d_in, const int* in_sizes, int n_in,
                              void* d_out, int out_size, void* d_ws, size_t ws_size,
                              hipStream_t stream) {
  const float* xyz = (const float*)d_in[0];
  const float* points = (const float*)d_in[1];
  float* out = (float*)d_out;
  float* new_xyz = out;
  float* new_points = out + (size_t)N_BATCH * NPOINT * 3;

  fps_kernel<<<N_BATCH, FPS_T, 0, stream>>>(xyz, new_xyz);
  ball_group_kernel<<<(N_BATCH * NPOINT) / 4, 256, 0, stream>>>(xyz, points, new_xyz, new_points);
}

// Round 13
// 1417.330 us; speedup vs baseline: 1.5612x; 1.0275x over previous
//
#include <hip/hip_runtime.h>
#include <cstdint>

#define N_PTS   8192
#define N_BATCH 8
#define NPOINT  2048
#define NSAMPLE 32
#define C_FEAT  64
#define R2      0.04f
#define FPS_T   1024
#define CH      (N_PTS / FPS_T)   // 8 points per thread = one chunk
#define NBINS   512               // 9-bit morton (3 bits/axis)
#define NWAVE   (FPS_T / 64)      // 16

static __device__ __forceinline__ uint32_t spread3(uint32_t v) {
  return (v & 1u) | ((v & 2u) << 2) | ((v & 4u) << 4);
}

static __device__ __forceinline__ uint32_t cell_of(float x, float y, float z) {
  int ix = (int)(x * 8.0f); ix = ix < 0 ? 0 : (ix > 7 ? 7 : ix);
  int iy = (int)(y * 8.0f); iy = iy < 0 ? 0 : (iy > 7 ? 7 : iy);
  int iz = (int)(z * 8.0f); iz = iz < 0 ? 0 : (iz > 7 ? 7 : iz);
  return spread3((uint32_t)ix) | (spread3((uint32_t)iy) << 1) | (spread3((uint32_t)iz) << 2);
}

// Wave-max step on packed positive f64 key via DPP (validated R2/R3/R6-R12).
#define DPP_MAXD(v, CTRL) do {                                                          \
  uint64_t u_ = __builtin_bit_cast(uint64_t, v);                                        \
  int lo_ = __builtin_amdgcn_update_dpp(0, (int)(uint32_t)u_,         CTRL, 0xF, 0xF, true); \
  int hi_ = __builtin_amdgcn_update_dpp(0, (int)(uint32_t)(u_ >> 32), CTRL, 0xF, 0xF, true); \
  double p_ = __builtin_bit_cast(double, ((uint64_t)(uint32_t)hi_ << 32) | (uint64_t)(uint32_t)lo_); \
  v = __builtin_fmax(v, p_);                                                            \
} while (0)

// ---------------------------------------------------------------------------
// FPS, one block per batch. R8 VERBATIM (best verified: 1306 us) except ONE
// fixed-path trim: lb slab distance via fmed3 (value-identical after the
// square; gate-only with 1e-5 margin; correctness-proven in R11/R12).
// Structure: f32 dist state, fmax tree + first-occurrence tie scan, DPP f64
// key reduce, wave-level skip with chunk c = t (Morton concentration keeps
// ~1 wave on the expensive path), parity slots, lane-parallel cross-wave
// reduce. R9 coord-carry / R10 transpose / R11 8-wave / R12 4096-sort all
// measured worse -- permanently retired.
// ---------------------------------------------------------------------------
__global__ __launch_bounds__(FPS_T) void fps_kernel(const float* __restrict__ xyz,
                                                    float* __restrict__ new_xyz) {
  __shared__ float sx[N_PTS], sy[N_PTS], sz[N_PTS];
  __shared__ int perm[N_PTS];          // setup only; reused as cent[] in loop
  __shared__ uint32_t bins[NBINS];
  __shared__ double pkey[2][NWAVE];
  float* cent = (float*)perm;          // [NPOINT*3] = 24 KB < 32 KB

  const int b = blockIdx.x;
  const int t = threadIdx.x;
  const int lane = t & 63;
  const int w = t >> 6;
  const float* xb = xyz + (size_t)b * N_PTS * 3;

  // ---- setup: stage coords ----
  for (int e = t; e < N_PTS * 3; e += FPS_T) {
    float v = xb[e];
    int p = e / 3, c = e - 3 * p;
    if (c == 0) sx[p] = v;
    else if (c == 1) sy[p] = v;
    else sz[p] = v;
  }
  if (t < NBINS) bins[t] = 0;
  __syncthreads();

  // ---- counting sort by morton cell: histogram ----
#pragma unroll
  for (int k = 0; k < CH; ++k) {
    int p = k * FPS_T + t;
    atomicAdd(&bins[cell_of(sx[p], sy[p], sz[p])], 1u);
  }
  __syncthreads();

  // ---- exclusive scan of 512 bins (wave 0, in place) ----
  if (t < 64) {
    uint32_t v[8], e[8], run = 0;
#pragma unroll
    for (int j = 0; j < 8; ++j) v[j] = bins[t * 8 + j];
#pragma unroll
    for (int j = 0; j < 8; ++j) { e[j] = run; run += v[j]; }
    uint32_t inc = run;
#pragma unroll
    for (int off = 1; off < 64; off <<= 1) {
      uint32_t o = __shfl_up(inc, off, 64);
      if (t >= off) inc += o;
    }
    uint32_t base = inc - run;
#pragma unroll
    for (int j = 0; j < 8; ++j) bins[t * 8 + j] = base + e[j];
  }
  __syncthreads();

  // ---- scatter permutation ----
#pragma unroll
  for (int k = 0; k < CH; ++k) {
    int p = k * FPS_T + t;
    uint32_t pos = atomicAdd(&bins[cell_of(sx[p], sy[p], sz[p])], 1u);
    perm[pos] = p;
  }
  __syncthreads();

  // ---- load chunk into registers (c = t: Morton-concentrated), bbox ----
  float rx[CH], ry[CH], rz[CH], dist[CH];
  uint32_t ridx[CH];
#pragma unroll
  for (int j = 0; j < CH; ++j) {
    int p = perm[CH * t + j];
    ridx[j] = (uint32_t)p;
    rx[j] = sx[p]; ry[j] = sy[p]; rz[j] = sz[p];
    dist[j] = __builtin_inff();
  }
  float bnx = rx[0], bxx = rx[0], bny = ry[0], bxy = ry[0], bnz = rz[0], bxz = rz[0];
#pragma unroll
  for (int j = 1; j < CH; ++j) {
    bnx = fminf(bnx, rx[j]); bxx = fmaxf(bxx, rx[j]);
    bny = fminf(bny, ry[j]); bxy = fmaxf(bxy, ry[j]);
    bnz = fminf(bnz, rz[j]); bxz = fmaxf(bxz, rz[j]);
  }
  __syncthreads();   // perm fully consumed; cent alias is now safe

  float cmax = __builtin_inff();   // chunk max dist (cached)
  uint32_t cidx = 0;               // chunk argmax orig idx (cached)
  double wkey = 0.0;               // cached wave-reduced key (lane 63 valid)
  int far = 0;

  for (int it = 0; it < NPOINT; ++it) {
    float cx = sx[far], cy = sy[far], cz = sz[far];
    if (t == 0) {   // LDS staging only -- no global store in the loop
      cent[it * 3 + 0] = cx;
      cent[it * 3 + 1] = cy;
      cent[it * 3 + 2] = cz;
    }

    // conservative lower bound of any d2 in this chunk: slab distance via
    // med3 (sign-free, squares away); gate-only, 1e-5 margin >> fp error
    float gx = cx - __builtin_amdgcn_fmed3f(cx, bnx, bxx);
    float gy = cy - __builtin_amdgcn_fmed3f(cy, bny, bxy);
    float gz = cz - __builtin_amdgcn_fmed3f(cz, bnz, bxz);
    float lb = gx * gx + gy * gy + gz * gz;

    bool act = !(lb * 0.99999f >= cmax);
    uint64_t am = __ballot(act);
    if (am != 0) {     // wave-uniform: some lane's cached key changes
      if (act) {
        {
#pragma clang fp contract(off)
#pragma unroll
          for (int j = 0; j < CH; ++j) {
            float dx = rx[j] - cx;
            float a = dx * dx;
            float dy = ry[j] - cy;
            a = a + dy * dy;         // exact left-to-right, no FMA
            float dz = rz[j] - cz;
            a = a + dz * dz;
            dist[j] = fminf(dist[j], a);
          }
        }
        // chunk max (tree) + first-occurrence (min orig idx) tie resolution
        float m0 = fmaxf(dist[0], dist[1]), m1 = fmaxf(dist[2], dist[3]);
        float m2 = fmaxf(dist[4], dist[5]), m3 = fmaxf(dist[6], dist[7]);
        cmax = fmaxf(fmaxf(m0, m1), fmaxf(m2, m3));
        uint32_t mi = 0xFFFFFFFFu;
#pragma unroll
        for (int j = 0; j < CH; ++j) {
          uint32_t cand = ridx[j] < mi ? ridx[j] : mi;
          mi = (dist[j] == cmax) ? cand : mi;
        }
        cidx = mi;
      }
      // wave reduce over ALL lanes' cached keys (active lanes just updated)
      double key = __builtin_bit_cast(double,
          ((uint64_t)__builtin_bit_cast(uint32_t, cmax) << 32) |
          (uint64_t)(0xFFFFFFFFu - cidx));
      DPP_MAXD(key, 0x111);   // row_shr 1
      DPP_MAXD(key, 0x112);   // row_shr 2
      DPP_MAXD(key, 0x114);   // row_shr 4
      DPP_MAXD(key, 0x118);   // row_shr 8
      DPP_MAXD(key, 0x142);   // row_bcast 15
      DPP_MAXD(key, 0x143);   // row_bcast 31  -> lane 63 has wave max
      wkey = key;             // cache (lane 63's copy is the wave max)
    }
    if (lane == 63) pkey[it & 1][w] = wkey;
    __syncthreads();

    // lane-parallel cross-wave reduce: lane reads slot (lane&15); 4-step DPP
    // row-reduce puts the max of all 16 slots in lane 15 of every row.
    double g = pkey[it & 1][lane & 15];
    DPP_MAXD(g, 0x111);
    DPP_MAXD(g, 0x112);
    DPP_MAXD(g, 0x114);
    DPP_MAXD(g, 0x118);
    uint64_t gu = __builtin_bit_cast(uint64_t, g);
    uint32_t glo = (uint32_t)__builtin_amdgcn_readlane((int)(uint32_t)gu, 15);
    far = (int)(0xFFFFFFFFu - glo);
  }

  // ---- one-time coalesced copy-out of staged centroids ----
  __syncthreads();
  float* ob = new_xyz + (size_t)b * NPOINT * 3;
  for (int e = t; e < NPOINT * 3; e += FPS_T) ob[e] = cent[e];
}

// ---------------------------------------------------------------------------
// Ball query + gather + concat, one wave per query (unchanged, verified).
// ---------------------------------------------------------------------------
__global__ __launch_bounds__(256) void ball_group_kernel(const float* __restrict__ xyz,
                                                         const float* __restrict__ points,
                                                         const float* __restrict__ new_xyz,
                                                         float* __restrict__ out_np) {
  __shared__ int list[4][NSAMPLE];
  const int wslot = threadIdx.x >> 6;
  const int lane = threadIdx.x & 63;
  const int qg = blockIdx.x * 4 + wslot;
  const int b = qg >> 11;

  const float* xb = xyz + (size_t)b * N_PTS * 3;
  const float* nq = new_xyz + (size_t)qg * 3;
  const float cqx = nq[0], cqy = nq[1], cqz = nq[2];

  int K = 0;
  {
#pragma clang fp contract(off)
    for (int c = 0; c < N_PTS / 64; ++c) {
      const int pt = c * 64 + lane;
      const float* p = xb + pt * 3;
      float dx = cqx - p[0];
      float dy = cqy - p[1];
      float dz = cqz - p[2];
      float d2 = dx * dx;
      d2 = d2 + dy * dy;
      d2 = d2 + dz * dz;
      bool in = d2 < R2;
      unsigned long long mask = __ballot(in);
      if (in) {
        int rank = __builtin_amdgcn_mbcnt_hi((uint32_t)(mask >> 32),
                     __builtin_amdgcn_mbcnt_lo((uint32_t)mask, 0));
        int s = K + rank;
        if (s < NSAMPLE) list[wslot][s] = pt;
      }
      K += (int)__popcll(mask);
      if (K >= NSAMPLE) break;   // wave-uniform
    }
  }
  __builtin_amdgcn_wave_barrier();
  int Kc = K < NSAMPLE ? K : NSAMPLE;
  int first = list[wslot][0];
  if (lane >= Kc && lane < NSAMPLE) list[wslot][lane] = first;
  __builtin_amdgcn_wave_barrier();

  const float* pb = points + (size_t)b * N_PTS * C_FEAT;
  float* oq = out_np + (size_t)qg * (NSAMPLE * 67);
  for (int r = 0; r < 34; ++r) {
    int tt = r * 64 + lane;
    if (tt < NSAMPLE * 67) {
      int s = tt / 67;
      int f = tt - s * 67;
      int idx = list[wslot][s];
      float val;
      if (f < 3) {
        float cf = (f == 0) ? cqx : ((f == 1) ? cqy : cqz);
        val = xb[idx * 3 + f] - cf;
      } else {
        val = pb[(size_t)idx * C_FEAT + (f - 3)];
      }
      oq[tt] = val;
    }
  }
}

extern "C" void kernel_launch(void* const* d_in, const int* in_sizes, int n_in,
                              void* d_out, int out_size, void* d_ws, size_t ws_size,
                              hipStream_t stream) {
  const float* xyz = (const float*)d_in[0];
  const float* points = (const float*)d_in[1];
  float* out = (float*)d_out;
  float* new_xyz = out;
  float* new_points = out + (size_t)N_BATCH * NPOINT * 3;

  fps_kernel<<<N_BATCH, FPS_T, 0, stream>>>(xyz, new_xyz);
  ball_group_kernel<<<(N_BATCH * NPOINT) / 4, 256, 0, stream>>>(xyz, points, new_xyz, new_points);
}

// Round 14
// 1370.292 us; speedup vs baseline: 1.6148x; 1.0343x over previous
//
#include <hip/hip_runtime.h>
#include <cstdint>

#define N_PTS   8192
#define N_BATCH 8
#define NPOINT  2048
#define NSAMPLE 32
#define C_FEAT  64
#define R2      0.04f
#define FPS_T   1024
#define CH      (N_PTS / FPS_T)   // 8 points per thread = one chunk
#define NBINS   512               // 9-bit morton (3 bits/axis)
#define NWAVE   (FPS_T / 64)      // 16

static __device__ __forceinline__ uint32_t spread3(uint32_t v) {
  return (v & 1u) | ((v & 2u) << 2) | ((v & 4u) << 4);
}

static __device__ __forceinline__ uint32_t cell_of(float x, float y, float z) {
  int ix = (int)(x * 8.0f); ix = ix < 0 ? 0 : (ix > 7 ? 7 : ix);
  int iy = (int)(y * 8.0f); iy = iy < 0 ? 0 : (iy > 7 ? 7 : iy);
  int iz = (int)(z * 8.0f); iz = iz < 0 ? 0 : (iz > 7 ? 7 : iz);
  return spread3((uint32_t)ix) | (spread3((uint32_t)iy) << 1) | (spread3((uint32_t)iz) << 2);
}

// Wave-max step on packed positive f64 key via DPP (validated R2/R3/R6-R13).
#define DPP_MAXD(v, CTRL) do {                                                          \
  uint64_t u_ = __builtin_bit_cast(uint64_t, v);                                        \
  int lo_ = __builtin_amdgcn_update_dpp(0, (int)(uint32_t)u_,         CTRL, 0xF, 0xF, true); \
  int hi_ = __builtin_amdgcn_update_dpp(0, (int)(uint32_t)(u_ >> 32), CTRL, 0xF, 0xF, true); \
  double p_ = __builtin_bit_cast(double, ((uint64_t)(uint32_t)hi_ << 32) | (uint64_t)(uint32_t)lo_); \
  v = __builtin_fmax(v, p_);                                                            \
} while (0)

// ---------------------------------------------------------------------------
// FPS, one block per batch. R8 VERBATIM — measured optimum (1306 us).
// f32 dist state, fmax tree + first-occurrence tie scan, DPP f64 key reduce,
// wave-level skip with chunk c = t (Morton concentration keeps ~1 wave on
// the expensive path), parity slots, lane-parallel cross-wave reduce, exact
// bbox pruning with fmaxf slab distance. Retired by measurement: coord-carry
// (R9 +47%), ownership transpose (R10 +64%), 8-wave (R11 +52%), 4096-cell
// sort (R12 +7%), fmed3 lb (R13 +3%).
// ---------------------------------------------------------------------------
__global__ __launch_bounds__(FPS_T) void fps_kernel(const float* __restrict__ xyz,
                                                    float* __restrict__ new_xyz) {
  __shared__ float sx[N_PTS], sy[N_PTS], sz[N_PTS];
  __shared__ int perm[N_PTS];          // setup only; reused as cent[] in loop
  __shared__ uint32_t bins[NBINS];
  __shared__ double pkey[2][NWAVE];
  float* cent = (float*)perm;          // [NPOINT*3] = 24 KB < 32 KB

  const int b = blockIdx.x;
  const int t = threadIdx.x;
  const int lane = t & 63;
  const int w = t >> 6;
  const float* xb = xyz + (size_t)b * N_PTS * 3;

  // ---- setup: stage coords ----
  for (int e = t; e < N_PTS * 3; e += FPS_T) {
    float v = xb[e];
    int p = e / 3, c = e - 3 * p;
    if (c == 0) sx[p] = v;
    else if (c == 1) sy[p] = v;
    else sz[p] = v;
  }
  if (t < NBINS) bins[t] = 0;
  __syncthreads();

  // ---- counting sort by morton cell: histogram ----
#pragma unroll
  for (int k = 0; k < CH; ++k) {
    int p = k * FPS_T + t;
    atomicAdd(&bins[cell_of(sx[p], sy[p], sz[p])], 1u);
  }
  __syncthreads();

  // ---- exclusive scan of 512 bins (wave 0, in place) ----
  if (t < 64) {
    uint32_t v[8], e[8], run = 0;
#pragma unroll
    for (int j = 0; j < 8; ++j) v[j] = bins[t * 8 + j];
#pragma unroll
    for (int j = 0; j < 8; ++j) { e[j] = run; run += v[j]; }
    uint32_t inc = run;
#pragma unroll
    for (int off = 1; off < 64; off <<= 1) {
      uint32_t o = __shfl_up(inc, off, 64);
      if (t >= off) inc += o;
    }
    uint32_t base = inc - run;
#pragma unroll
    for (int j = 0; j < 8; ++j) bins[t * 8 + j] = base + e[j];
  }
  __syncthreads();

  // ---- scatter permutation ----
#pragma unroll
  for (int k = 0; k < CH; ++k) {
    int p = k * FPS_T + t;
    uint32_t pos = atomicAdd(&bins[cell_of(sx[p], sy[p], sz[p])], 1u);
    perm[pos] = p;
  }
  __syncthreads();

  // ---- load chunk into registers (c = t: Morton-concentrated), bbox ----
  float rx[CH], ry[CH], rz[CH], dist[CH];
  uint32_t ridx[CH];
#pragma unroll
  for (int j = 0; j < CH; ++j) {
    int p = perm[CH * t + j];
    ridx[j] = (uint32_t)p;
    rx[j] = sx[p]; ry[j] = sy[p]; rz[j] = sz[p];
    dist[j] = __builtin_inff();
  }
  float bnx = rx[0], bxx = rx[0], bny = ry[0], bxy = ry[0], bnz = rz[0], bxz = rz[0];
#pragma unroll
  for (int j = 1; j < CH; ++j) {
    bnx = fminf(bnx, rx[j]); bxx = fmaxf(bxx, rx[j]);
    bny = fminf(bny, ry[j]); bxy = fmaxf(bxy, ry[j]);
    bnz = fminf(bnz, rz[j]); bxz = fmaxf(bxz, rz[j]);
  }
  __syncthreads();   // perm fully consumed; cent alias is now safe

  float cmax = __builtin_inff();   // chunk max dist (cached)
  uint32_t cidx = 0;               // chunk argmax orig idx (cached)
  double wkey = 0.0;               // cached wave-reduced key (lane 63 valid)
  int far = 0;

  for (int it = 0; it < NPOINT; ++it) {
    float cx = sx[far], cy = sy[far], cz = sz[far];
    if (t == 0) {   // LDS staging only -- no global store in the loop
      cent[it * 3 + 0] = cx;
      cent[it * 3 + 1] = cy;
      cent[it * 3 + 2] = cz;
    }

    // conservative lower bound of any d2 in this chunk (margin 1e-5 >> fp err)
    float gx = fmaxf(fmaxf(bnx - cx, cx - bxx), 0.0f);
    float gy = fmaxf(fmaxf(bny - cy, cy - bxy), 0.0f);
    float gz = fmaxf(fmaxf(bnz - cz, cz - bxz), 0.0f);
    float lb = gx * gx + gy * gy + gz * gz;

    bool act = !(lb * 0.99999f >= cmax);
    uint64_t am = __ballot(act);
    if (am != 0) {     // wave-uniform: some lane's cached key changes
      if (act) {
        {
#pragma clang fp contract(off)
#pragma unroll
          for (int j = 0; j < CH; ++j) {
            float dx = rx[j] - cx;
            float a = dx * dx;
            float dy = ry[j] - cy;
            a = a + dy * dy;         // exact left-to-right, no FMA
            float dz = rz[j] - cz;
            a = a + dz * dz;
            dist[j] = fminf(dist[j], a);
          }
        }
        // chunk max (tree) + first-occurrence (min orig idx) tie resolution
        float m0 = fmaxf(dist[0], dist[1]), m1 = fmaxf(dist[2], dist[3]);
        float m2 = fmaxf(dist[4], dist[5]), m3 = fmaxf(dist[6], dist[7]);
        cmax = fmaxf(fmaxf(m0, m1), fmaxf(m2, m3));
        uint32_t mi = 0xFFFFFFFFu;
#pragma unroll
        for (int j = 0; j < CH; ++j) {
          uint32_t cand = ridx[j] < mi ? ridx[j] : mi;
          mi = (dist[j] == cmax) ? cand : mi;
        }
        cidx = mi;
      }
      // wave reduce over ALL lanes' cached keys (active lanes just updated)
      double key = __builtin_bit_cast(double,
          ((uint64_t)__builtin_bit_cast(uint32_t, cmax) << 32) |
          (uint64_t)(0xFFFFFFFFu - cidx));
      DPP_MAXD(key, 0x111);   // row_shr 1
      DPP_MAXD(key, 0x112);   // row_shr 2
      DPP_MAXD(key, 0x114);   // row_shr 4
      DPP_MAXD(key, 0x118);   // row_shr 8
      DPP_MAXD(key, 0x142);   // row_bcast 15
      DPP_MAXD(key, 0x143);   // row_bcast 31  -> lane 63 has wave max
      wkey = key;             // cache (lane 63's copy is the wave max)
    }
    if (lane == 63) pkey[it & 1][w] = wkey;
    __syncthreads();

    // lane-parallel cross-wave reduce: lane reads slot (lane&15); 4-step DPP
    // row-reduce puts the max of all 16 slots in lane 15 of every row.
    double g = pkey[it & 1][lane & 15];
    DPP_MAXD(g, 0x111);
    DPP_MAXD(g, 0x112);
    DPP_MAXD(g, 0x114);
    DPP_MAXD(g, 0x118);
    uint64_t gu = __builtin_bit_cast(uint64_t, g);
    uint32_t glo = (uint32_t)__builtin_amdgcn_readlane((int)(uint32_t)gu, 15);
    far = (int)(0xFFFFFFFFu - glo);
  }

  // ---- one-time coalesced copy-out of staged centroids ----
  __syncthreads();
  float* ob = new_xyz + (size_t)b * NPOINT * 3;
  for (int e = t; e < NPOINT * 3; e += FPS_T) ob[e] = cent[e];
}

// ---------------------------------------------------------------------------
// Ball query + gather + concat, one wave per query. Ball-query scan verbatim
// (verified R1-R13). Output loop reworked to float2 stores: 17 iterations of
// 8B/lane (512B/wave-store) instead of 34 x 4B/lane. Element values computed
// identically (same gathers, same subtraction) -> bit-identical output.
// Alignment: query tile = 2144 floats (8B-aligned base), pairs start at even
// element offsets -> every float2 store is naturally 8B-aligned.
// ---------------------------------------------------------------------------
__global__ __launch_bounds__(256) void ball_group_kernel(const float* __restrict__ xyz,
                                                         const float* __restrict__ points,
                                                         const float* __restrict__ new_xyz,
                                                         float* __restrict__ out_np) {
  __shared__ int list[4][NSAMPLE];
  const int wslot = threadIdx.x >> 6;
  const int lane = threadIdx.x & 63;
  const int qg = blockIdx.x * 4 + wslot;
  const int b = qg >> 11;

  const float* xb = xyz + (size_t)b * N_PTS * 3;
  const float* nq = new_xyz + (size_t)qg * 3;
  const float cqx = nq[0], cqy = nq[1], cqz = nq[2];

  int K = 0;
  {
#pragma clang fp contract(off)
    for (int c = 0; c < N_PTS / 64; ++c) {
      const int pt = c * 64 + lane;
      const float* p = xb + pt * 3;
      float dx = cqx - p[0];
      float dy = cqy - p[1];
      float dz = cqz - p[2];
      float d2 = dx * dx;
      d2 = d2 + dy * dy;
      d2 = d2 + dz * dz;
      bool in = d2 < R2;
      unsigned long long mask = __ballot(in);
      if (in) {
        int rank = __builtin_amdgcn_mbcnt_hi((uint32_t)(mask >> 32),
                     __builtin_amdgcn_mbcnt_lo((uint32_t)mask, 0));
        int s = K + rank;
        if (s < NSAMPLE) list[wslot][s] = pt;
      }
      K += (int)__popcll(mask);
      if (K >= NSAMPLE) break;   // wave-uniform
    }
  }
  __builtin_amdgcn_wave_barrier();
  int Kc = K < NSAMPLE ? K : NSAMPLE;
  int first = list[wslot][0];
  if (lane >= Kc && lane < NSAMPLE) list[wslot][lane] = first;
  __builtin_amdgcn_wave_barrier();

  const float* pb = points + (size_t)b * N_PTS * C_FEAT;
  float* oq = out_np + (size_t)qg * (NSAMPLE * 67);
#pragma unroll
  for (int r = 0; r < 17; ++r) {
    int pp = r * 64 + lane;                 // float2 index, 0..1071 valid
    if (pp < (NSAMPLE * 67) / 2) {
      int e0 = pp * 2;
      int s0 = e0 / 67;
      int f0 = e0 - s0 * 67;
      int s1 = (f0 == 66) ? s0 + 1 : s0;    // e1 = e0+1 may cross slot
      int f1 = (f0 == 66) ? 0 : f0 + 1;
      int i0 = list[wslot][s0];
      int i1 = list[wslot][s1];
      float v0, v1;
      if (f0 < 3) {
        float cf = (f0 == 0) ? cqx : ((f0 == 1) ? cqy : cqz);
        v0 = xb[i0 * 3 + f0] - cf;
      } else {
        v0 = pb[(size_t)i0 * C_FEAT + (f0 - 3)];
      }
      if (f1 < 3) {
        float cf = (f1 == 0) ? cqx : ((f1 == 1) ? cqy : cqz);
        v1 = xb[i1 * 3 + f1] - cf;
      } else {
        v1 = pb[(size_t)i1 * C_FEAT + (f1 - 3)];
      }
      *reinterpret_cast<float2*>(&oq[e0]) = make_float2(v0, v1);
    }
  }
}

extern "C" void kernel_launch(void* const* d_in, const int* in_sizes, int n_in,
                              void* d_out, int out_size, void* d_ws, size_t ws_size,
                              hipStream_t stream) {
  const float* xyz = (const float*)d_in[0];
  const float* points = (const float*)d_in[1];
  float* out = (float*)d_out;
  float* new_xyz = out;
  float* new_points = out + (size_t)N_BATCH * NPOINT * 3;

  fps_kernel<<<N_BATCH, FPS_T, 0, stream>>>(xyz, new_xyz);
  ball_group_kernel<<<(N_BATCH * NPOINT) / 4, 256, 0, stream>>>(xyz, points, new_xyz, new_points);
}